// Round 7
// baseline (153.609 us; speedup 1.0000x reference)
//
#include <hip/hip_runtime.h>

typedef __fp16 f16;
typedef f16  h8 __attribute__((ext_vector_type(8)));
typedef float f4 __attribute__((ext_vector_type(4)));
typedef unsigned u32t;

#define NBLOCKS 1024
#define WPB 4
#define SPW 64
#define NBATCH 4
#define K2L 2.8853900817779268f   // 2*log2(e):  e^{2a} = 2^{K2L*a}

union H8u { h8 v; u32t u[4]; };

__device__ __forceinline__ u32t pk2(float a, float b) {
    return __builtin_bit_cast(u32t, __builtin_amdgcn_cvt_pkrtz(a, b));
}

// h = tanh(a), g = sech^2(a) given t = K2L*a (E = 2^t = e^{2a}); NaN-free at sat.
__device__ __forceinline__ void tanh_sech2_t(float t, float& h, float& g) {
    float E = __builtin_amdgcn_exp2f(t);
    float inv = __builtin_amdgcn_rcpf(E + 1.f);
    float u = inv + inv;
    h = 1.f - u;
    g = u * (2.f - u);
}

#define MF(A, B, C) C = __builtin_amdgcn_mfma_f32_16x16x32_f16(A, B, C, 0, 0, 0)

// NOTE (R5/R6 lesson): fragment arrays-of-union with piecewise .u[] writes get
// demoted to scratch (FETCH 2.3MB -> 360MB). All fragments below are NAMED h8
// vars assembled whole from a local H8u temp; mt/kk loops are macro-expanded.
__global__ __launch_bounds__(256, 3) void pinn_mfma_kernel(
    const float* __restrict__ x_r, const float* __restrict__ sigma_r,
    const float* __restrict__ W1, const float* __restrict__ b1,
    const float* __restrict__ W2, const float* __restrict__ b2,
    const float* __restrict__ W3, const float* __restrict__ b3,
    const float* __restrict__ W4, float* __restrict__ out)
{
    // Pre-packed f16 A-fragments, frag layout: F[mat][frag=2*mt+kk][lane] = 4 u32.
    // mat 0: A2[m][k] = W2[k][m] (identity k-map). mat 1: A3 under pi3 so the
    // L2 C -> L3 B repack is same-lane pure-register (no LDS exchange).
    __shared__ uint4 F[2][8][64];          // 16 KB
    __shared__ f4 Wk[64];                  // (K*w1x, K*w1y, K*w1z, K*b1)
    __shared__ f4 Wd[64];                  // (w1x, w1y, w1z, -2*Q1)
    __shared__ f4 BbK2[16], BbK3[16], W4v[16];

    const int tid = threadIdx.x, lane = tid & 63, wv = tid >> 6;
    const int sb = lane & 15;   // sample slot (B/C col)
    const int q  = lane >> 4;   // lane quarter

    if (tid < 64) {
        float wx = W1[tid], wy = W1[64 + tid], wz = W1[128 + tid];
        f4 a; a[0] = K2L * wx; a[1] = K2L * wy; a[2] = K2L * wz; a[3] = K2L * b1[tid];
        Wk[tid] = a;
        f4 d; d[0] = wx; d[1] = wy; d[2] = wz; d[3] = -2.f * (wx*wx + wy*wy + wz*wz);
        Wd[tid] = d;
        ((float*)BbK2)[tid] = K2L * b2[tid];
        ((float*)BbK3)[tid] = K2L * b3[tid];
        ((float*)W4v)[tid]  = W4[tid];
    }
    // Fill F: 1024 (mat,frag,lane) slots, 4 per thread.
#pragma unroll
    for (int i = 0; i < 4; ++i) {
        const int slot = i * 256 + tid;
        const int mat = slot >> 9, fl = slot & 511;
        const int fg = fl >> 6, ln = fl & 63;
        const int mt = fg >> 1, kk = fg & 1;
        const int qq = ln >> 4, col = 16 * mt + (ln & 15);
        u32t v0, v1, v2, v3;
        if (mat == 0) {
            const int r0 = (32*kk + 8*qq) * 64 + col;
            v0 = pk2(W2[r0],       W2[r0 + 64]);
            v1 = pk2(W2[r0 + 128], W2[r0 + 192]);
            v2 = pk2(W2[r0 + 256], W2[r0 + 320]);
            v3 = pk2(W2[r0 + 384], W2[r0 + 448]);
        } else {
            const int rb = (32*kk + 4*qq) * 64 + col;
            v0 = pk2(W3[rb],            W3[rb + 64]);
            v1 = pk2(W3[rb + 128],      W3[rb + 192]);
            v2 = pk2(W3[rb + 1024],     W3[rb + 1088]);
            v3 = pk2(W3[rb + 1152],     W3[rb + 1216]);
        }
        F[mat][fg][ln] = make_uint4(v0, v1, v2, v3);
    }
    __syncthreads();   // the only barrier

    const long sbase = ((long)blockIdx.x * WPB + wv) * SPW;
    float nx0 = x_r[(sbase + sb) * 3], nx1 = x_r[(sbase + sb) * 3 + 1],
          nx2 = x_r[(sbase + sb) * 3 + 2], nsg = sigma_r[sbase + sb];

// layer 1 -> one B2 fragment (kk = KK), assembled whole.
#define L1K(KK, BH, BX, BY, BZ, BS) {                                             \
    H8u th, tx, ty, tz, ts;                                                       \
    _Pragma("unroll")                                                             \
    for (int p = 0; p < 4; ++p) {                                                 \
        float hv[2], xv[2], yv[2], zv[2], sv[2];                                  \
        _Pragma("unroll")                                                         \
        for (int o = 0; o < 2; ++o) {                                             \
            const int uu = 32 * (KK) + 8 * q + 2 * p + o;                         \
            const f4 wk = Wk[uu], wd = Wd[uu];                                    \
            const float tt = fmaf(wk[0], x0, fmaf(wk[1], x1, fmaf(wk[2], x2, wk[3]))); \
            float h, g; tanh_sech2_t(tt, h, g);                                   \
            hv[o] = h; xv[o] = g * wd[0]; yv[o] = g * wd[1]; zv[o] = g * wd[2];   \
            sv[o] = (h * g) * wd[3];                                              \
        }                                                                         \
        th.u[p] = pk2(hv[0], hv[1]); tx.u[p] = pk2(xv[0], xv[1]);                 \
        ty.u[p] = pk2(yv[0], yv[1]); tz.u[p] = pk2(zv[0], zv[1]);                 \
        ts.u[p] = pk2(sv[0], sv[1]);                                              \
    }                                                                             \
    BH = th.v; BX = tx.v; BY = ty.v; BZ = tz.v; BS = ts.v; }

// layer 2, one mt tile: 10 MFMA -> NL -> write 2 u32 words (PO, PO+1) per state
// into the H8u temps TH..TS (assembled into named h8 after both halves).
#define L2HALF(MT, PO, TH, TX, TY, TZ, TS) {                                      \
    f4 Ch = {0,0,0,0}, Cx = {0,0,0,0}, Cy = {0,0,0,0}, Cz = {0,0,0,0}, Cs = {0,0,0,0}; \
    { const h8 A0 = *(const h8*)&F[0][2 * (MT)][lane];                            \
      MF(A0, Bh0, Ch); MF(A0, Bx0, Cx); MF(A0, By0, Cy); MF(A0, Bz0, Cz); MF(A0, Bs0, Cs); } \
    { const h8 A1 = *(const h8*)&F[0][2 * (MT) + 1][lane];                        \
      MF(A1, Bh1, Ch); MF(A1, Bx1, Cx); MF(A1, By1, Cy); MF(A1, Bz1, Cz); MF(A1, Bs1, Cs); } \
    const f4 bb = BbK2[4 * (MT) + q];                                             \
    float oh[4], ox[4], oy[4], oz[4], os[4];                                      \
    _Pragma("unroll")                                                             \
    for (int r = 0; r < 4; ++r) {                                                 \
        float h, g; tanh_sech2_t(fmaf(Ch[r], K2L, bb[r]), h, g);                  \
        const float ax = Cx[r], ay = Cy[r], az = Cz[r];                           \
        const float qq = fmaf(ax, ax, fmaf(ay, ay, az * az));                     \
        oh[r] = h; ox[r] = g * ax; oy[r] = g * ay; oz[r] = g * az;                \
        os[r] = g * fmaf(-(h + h), qq, Cs[r]);                                    \
    }                                                                             \
    TH.u[(PO)] = pk2(oh[0], oh[1]); TH.u[(PO) + 1] = pk2(oh[2], oh[3]);           \
    TX.u[(PO)] = pk2(ox[0], ox[1]); TX.u[(PO) + 1] = pk2(ox[2], ox[3]);           \
    TY.u[(PO)] = pk2(oy[0], oy[1]); TY.u[(PO) + 1] = pk2(oy[2], oy[3]);           \
    TZ.u[(PO)] = pk2(oz[0], oz[1]); TZ.u[(PO) + 1] = pk2(oz[2], oz[3]);           \
    TS.u[(PO)] = pk2(os[0], os[1]); TS.u[(PO) + 1] = pk2(os[2], os[3]); }

// layer 3, one mt tile: 10 MFMA -> NL -> dot with W4 into tot.
#define L3MT(MT) {                                                                \
    f4 Ch = {0,0,0,0}, Cx = {0,0,0,0}, Cy = {0,0,0,0}, Cz = {0,0,0,0}, Cs = {0,0,0,0}; \
    { const h8 A0 = *(const h8*)&F[1][2 * (MT)][lane];                            \
      MF(A0, Nh0, Ch); MF(A0, Nx0, Cx); MF(A0, Ny0, Cy); MF(A0, Nz0, Cz); MF(A0, Ns0, Cs); } \
    { const h8 A1 = *(const h8*)&F[1][2 * (MT) + 1][lane];                        \
      MF(A1, Nh1, Ch); MF(A1, Nx1, Cx); MF(A1, Ny1, Cy); MF(A1, Nz1, Cz); MF(A1, Ns1, Cs); } \
    const f4 bb = BbK3[4 * (MT) + q], w4 = W4v[4 * (MT) + q];                     \
    _Pragma("unroll")                                                             \
    for (int r = 0; r < 4; ++r) {                                                 \
        float h, g; tanh_sech2_t(fmaf(Ch[r], K2L, bb[r]), h, g);                  \
        const float ax = Cx[r], ay = Cy[r], az = Cz[r];                           \
        const float qq = fmaf(ax, ax, fmaf(ay, ay, az * az));                     \
        const float sv = g * fmaf(-(h + h), qq, Cs[r]);                           \
        tot = fmaf(sv, w4[r], tot);                                               \
    } }

#pragma unroll 1
    for (int t = 0; t < NBATCH; ++t) {
        const float x0 = nx0, x1 = nx1, x2 = nx2, sg = nsg;
        const long sn = sbase + ((t + 1) & 3) * 16 + sb;   // wraps on last iter (benign)
        nx0 = x_r[sn * 3]; nx1 = x_r[sn * 3 + 1]; nx2 = x_r[sn * 3 + 2];
        nsg = sigma_r[sn];

        // ---- layer 1 straight into named B2 fragments ----
        h8 Bh0, Bh1, Bx0, Bx1, By0, By1, Bz0, Bz1, Bs0, Bs1;
        L1K(0, Bh0, Bx0, By0, Bz0, Bs0)
        L1K(1, Bh1, Bx1, By1, Bz1, Bs1)

        // ---- layer 2: 4 mt tiles -> named B3 fragments (same-lane pi3 repack) ----
        h8 Nh0, Nx0, Ny0, Nz0, Ns0, Nh1, Nx1, Ny1, Nz1, Ns1;
        {
            H8u th, tx, ty, tz, ts;
            L2HALF(0, 0, th, tx, ty, tz, ts)
            L2HALF(1, 2, th, tx, ty, tz, ts)
            Nh0 = th.v; Nx0 = tx.v; Ny0 = ty.v; Nz0 = tz.v; Ns0 = ts.v;
        }
        {
            H8u th, tx, ty, tz, ts;
            L2HALF(2, 0, th, tx, ty, tz, ts)
            L2HALF(3, 2, th, tx, ty, tz, ts)
            Nh1 = th.v; Nx1 = tx.v; Ny1 = ty.v; Nz1 = tz.v; Ns1 = ts.v;
        }

        // ---- layer 3 + W4 dot ----
        float tot = 0.f;
        L3MT(0) L3MT(1) L3MT(2) L3MT(3)

        tot += __shfl_xor(tot, 16);
        tot += __shfl_xor(tot, 32);
        if (lane < 16) out[sbase + t * 16 + sb] = sg * tot;
    }
}

extern "C" void kernel_launch(void* const* d_in, const int* in_sizes, int n_in,
                              void* d_out, int out_size, void* d_ws, size_t ws_size,
                              hipStream_t stream) {
    const float* x_r     = (const float*)d_in[0];
    const float* sigma_r = (const float*)d_in[1];
    const float* W1      = (const float*)d_in[2];
    const float* b1      = (const float*)d_in[3];
    const float* W2      = (const float*)d_in[4];
    const float* b2      = (const float*)d_in[5];
    const float* W3      = (const float*)d_in[6];
    const float* b3      = (const float*)d_in[7];
    const float* W4      = (const float*)d_in[8];
    float* out = (float*)d_out;

    pinn_mfma_kernel<<<NBLOCKS, 256, 0, stream>>>(
        x_r, sigma_r, W1, b1, W2, b2, W3, b3, W4, out);
}

// Round 8
// 150.924 us; speedup vs baseline: 1.0178x; 1.0178x over previous
//
#include <hip/hip_runtime.h>

typedef __fp16 f16;
typedef f16 h2 __attribute__((ext_vector_type(2)));
typedef f16 h4 __attribute__((ext_vector_type(4)));
typedef f16 h8 __attribute__((ext_vector_type(8)));
typedef float f4 __attribute__((ext_vector_type(4)));
typedef unsigned u32t;

#define NBLOCKS 1024
#define WPB 4
#define SPW 64
#define NBATCH 4
#define K2L 2.8853900817779268f   // 2*log2(e):  e^{2a} = 2^{K2L*a}

__device__ __forceinline__ h2 pkh(float a, float b) {
    return __builtin_amdgcn_cvt_pkrtz(a, b);     // v_cvt_pkrtz_f16_f32, SSA vector
}
__device__ __forceinline__ u32t pk2(float a, float b) {
    return __builtin_bit_cast(u32t, __builtin_amdgcn_cvt_pkrtz(a, b));
}
__device__ __forceinline__ h4 cat2(h2 a, h2 b) {
    return __builtin_shufflevector(a, b, 0, 1, 2, 3);
}
__device__ __forceinline__ h8 cat4(h4 a, h4 b) {
    return __builtin_shufflevector(a, b, 0, 1, 2, 3, 4, 5, 6, 7);
}

// h = tanh(a), g = sech^2(a) given t = K2L*a (E = 2^t = e^{2a}); NaN-free at sat.
__device__ __forceinline__ void tanh_sech2_t(float t, float& h, float& g) {
    float E = __builtin_amdgcn_exp2f(t);
    float inv = __builtin_amdgcn_rcpf(E + 1.f);
    float u = inv + inv;
    h = 1.f - u;
    g = u * (2.f - u);
}

#define MF(A, B, C) C = __builtin_amdgcn_mfma_f32_16x16x32_f16(A, B, C, 0, 0, 0)

// R5-R7 lesson: ANY union/array-based fragment assembly (H8u .u[] writes, even
// into named vars) became scratch "local memory": FETCH 2.3MB -> 360MB, 5x slow.
// This version builds every fragment with pure SSA vector ops (cvt_pkrtz -> h2,
// shufflevector concat) -- no allocas exist, scratch is impossible by construction.
__global__ __launch_bounds__(256, 3) void pinn_mfma_kernel(
    const float* __restrict__ x_r, const float* __restrict__ sigma_r,
    const float* __restrict__ W1, const float* __restrict__ b1,
    const float* __restrict__ W2, const float* __restrict__ b2,
    const float* __restrict__ W3, const float* __restrict__ b3,
    const float* __restrict__ W4, float* __restrict__ out)
{
    // Pre-packed f16 A-fragments, frag layout: F[mat][frag=2*mt+kk][lane] = 4 u32.
    // mat 0: A2[m][k] = W2[k][m] (identity k-map). mat 1: A3 under pi3 so the
    // L2 C -> L3 B repack is same-lane pure-register (no LDS exchange).
    __shared__ uint4 F[2][8][64];          // 16 KB
    __shared__ f4 Wk[64];                  // (K*w1x, K*w1y, K*w1z, K*b1)
    __shared__ f4 Wd[64];                  // (w1x, w1y, w1z, -2*Q1)
    __shared__ f4 BbK2[16], BbK3[16], W4v[16];

    const int tid = threadIdx.x, lane = tid & 63, wv = tid >> 6;
    const int sb = lane & 15;   // sample slot (B/C col)
    const int q  = lane >> 4;   // lane quarter

    if (tid < 64) {
        float wx = W1[tid], wy = W1[64 + tid], wz = W1[128 + tid];
        f4 a; a[0] = K2L * wx; a[1] = K2L * wy; a[2] = K2L * wz; a[3] = K2L * b1[tid];
        Wk[tid] = a;
        f4 d; d[0] = wx; d[1] = wy; d[2] = wz; d[3] = -2.f * (wx*wx + wy*wy + wz*wz);
        Wd[tid] = d;
        ((float*)BbK2)[tid] = K2L * b2[tid];
        ((float*)BbK3)[tid] = K2L * b3[tid];
        ((float*)W4v)[tid]  = W4[tid];
    }
    // Fill F: 1024 (mat,frag,lane) slots, 4 per thread.
#pragma unroll
    for (int i = 0; i < 4; ++i) {
        const int slot = i * 256 + tid;
        const int mat = slot >> 9, fl = slot & 511;
        const int fg = fl >> 6, ln = fl & 63;
        const int mt = fg >> 1, kk = fg & 1;
        const int qq = ln >> 4, col = 16 * mt + (ln & 15);
        u32t v0, v1, v2, v3;
        if (mat == 0) {
            const int r0 = (32*kk + 8*qq) * 64 + col;
            v0 = pk2(W2[r0],       W2[r0 + 64]);
            v1 = pk2(W2[r0 + 128], W2[r0 + 192]);
            v2 = pk2(W2[r0 + 256], W2[r0 + 320]);
            v3 = pk2(W2[r0 + 384], W2[r0 + 448]);
        } else {
            const int rb = (32*kk + 4*qq) * 64 + col;
            v0 = pk2(W3[rb],            W3[rb + 64]);
            v1 = pk2(W3[rb + 128],      W3[rb + 192]);
            v2 = pk2(W3[rb + 1024],     W3[rb + 1088]);
            v3 = pk2(W3[rb + 1152],     W3[rb + 1216]);
        }
        F[mat][fg][ln] = make_uint4(v0, v1, v2, v3);
    }
    __syncthreads();   // the only barrier

    const long sbase = ((long)blockIdx.x * WPB + wv) * SPW;
    float nx0 = x_r[(sbase + sb) * 3], nx1 = x_r[(sbase + sb) * 3 + 1],
          nx2 = x_r[(sbase + sb) * 3 + 2], nsg = sigma_r[sbase + sb];

// one layer-1 unit: named scalars H,GX,GY,GZ,SV (scoped by caller's block)
#define UNIT(U, H, GX, GY, GZ, SV)                                                \
    float H, GX, GY, GZ, SV; {                                                    \
        const f4 wk = Wk[(U)], wd = Wd[(U)];                                      \
        const float tt = fmaf(wk[0], x0, fmaf(wk[1], x1, fmaf(wk[2], x2, wk[3])));\
        float g; tanh_sech2_t(tt, H, g);                                          \
        GX = g * wd[0]; GY = g * wd[1]; GZ = g * wd[2]; SV = (H * g) * wd[3]; }

// layer 1 -> 5 named B2 fragments for k-chunk KK (unit = 32*KK + 8q + e)
#define L1K(KK, BH, BX, BY, BZ, BS)                                               \
    h8 BH, BX, BY, BZ, BS; {                                                      \
        const int ub = 32 * (KK) + 8 * q;                                         \
        UNIT(ub + 0, u0h, u0x, u0y, u0z, u0s) UNIT(ub + 1, u1h, u1x, u1y, u1z, u1s)\
        UNIT(ub + 2, u2h, u2x, u2y, u2z, u2s) UNIT(ub + 3, u3h, u3x, u3y, u3z, u3s)\
        UNIT(ub + 4, u4h, u4x, u4y, u4z, u4s) UNIT(ub + 5, u5h, u5x, u5y, u5z, u5s)\
        UNIT(ub + 6, u6h, u6x, u6y, u6z, u6s) UNIT(ub + 7, u7h, u7x, u7y, u7z, u7s)\
        BH = cat4(cat2(pkh(u0h,u1h), pkh(u2h,u3h)), cat2(pkh(u4h,u5h), pkh(u6h,u7h)));\
        BX = cat4(cat2(pkh(u0x,u1x), pkh(u2x,u3x)), cat2(pkh(u4x,u5x), pkh(u6x,u7x)));\
        BY = cat4(cat2(pkh(u0y,u1y), pkh(u2y,u3y)), cat2(pkh(u4y,u5y), pkh(u6y,u7y)));\
        BZ = cat4(cat2(pkh(u0z,u1z), pkh(u2z,u3z)), cat2(pkh(u4z,u5z), pkh(u6z,u7z)));\
        BS = cat4(cat2(pkh(u0s,u1s), pkh(u2s,u3s)), cat2(pkh(u4s,u5s), pkh(u6s,u7s)));}

// layer-2/3 pointwise for one C element -> named scalars
#define NLR(CH, CX, CY, CZ, CS, BB, OH, OX, OY, OZ, OS)                           \
    float OH, OX, OY, OZ, OS; {                                                   \
        float h, g; tanh_sech2_t(fmaf((CH), K2L, (BB)), h, g);                    \
        const float ax = (CX), ay = (CY), az = (CZ);                              \
        const float qn = fmaf(ax, ax, fmaf(ay, ay, az * az));                     \
        OH = h; OX = g * ax; OY = g * ay; OZ = g * az;                            \
        OS = g * fmaf(-(h + h), qn, (CS)); }

// layer 2, one mt tile: 10 MFMA -> NL -> one named h4 per state (pi3 quad)
#define L2MT(MT, QH, QX, QY, QZ, QS)                                              \
    h4 QH, QX, QY, QZ, QS; {                                                      \
        f4 Ch = {0,0,0,0}, Cx = {0,0,0,0}, Cy = {0,0,0,0}, Cz = {0,0,0,0}, Cs = {0,0,0,0};\
        { const h8 A0 = *(const h8*)&F[0][2 * (MT)][lane];                        \
          MF(A0, Bh0, Ch); MF(A0, Bx0, Cx); MF(A0, By0, Cy); MF(A0, Bz0, Cz); MF(A0, Bs0, Cs); }\
        { const h8 A1 = *(const h8*)&F[0][2 * (MT) + 1][lane];                    \
          MF(A1, Bh1, Ch); MF(A1, Bx1, Cx); MF(A1, By1, Cy); MF(A1, Bz1, Cz); MF(A1, Bs1, Cs); }\
        const f4 bb = BbK2[4 * (MT) + q];                                         \
        NLR(Ch[0], Cx[0], Cy[0], Cz[0], Cs[0], bb[0], o0h, o0x, o0y, o0z, o0s)    \
        NLR(Ch[1], Cx[1], Cy[1], Cz[1], Cs[1], bb[1], o1h, o1x, o1y, o1z, o1s)    \
        NLR(Ch[2], Cx[2], Cy[2], Cz[2], Cs[2], bb[2], o2h, o2x, o2y, o2z, o2s)    \
        NLR(Ch[3], Cx[3], Cy[3], Cz[3], Cs[3], bb[3], o3h, o3x, o3y, o3z, o3s)    \
        QH = cat2(pkh(o0h, o1h), pkh(o2h, o3h));                                  \
        QX = cat2(pkh(o0x, o1x), pkh(o2x, o3x));                                  \
        QY = cat2(pkh(o0y, o1y), pkh(o2y, o3y));                                  \
        QZ = cat2(pkh(o0z, o1z), pkh(o2z, o3z));                                  \
        QS = cat2(pkh(o0s, o1s), pkh(o2s, o3s)); }

// layer 3, one mt tile: 10 MFMA -> NL -> dot with W4 into tot
#define L3MT(MT) {                                                                \
        f4 Ch = {0,0,0,0}, Cx = {0,0,0,0}, Cy = {0,0,0,0}, Cz = {0,0,0,0}, Cs = {0,0,0,0};\
        { const h8 A0 = *(const h8*)&F[1][2 * (MT)][lane];                        \
          MF(A0, Nh0, Ch); MF(A0, Nx0, Cx); MF(A0, Ny0, Cy); MF(A0, Nz0, Cz); MF(A0, Ns0, Cs); }\
        { const h8 A1 = *(const h8*)&F[1][2 * (MT) + 1][lane];                    \
          MF(A1, Nh1, Ch); MF(A1, Nx1, Cx); MF(A1, Ny1, Cy); MF(A1, Nz1, Cz); MF(A1, Ns1, Cs); }\
        const f4 bb = BbK3[4 * (MT) + q], w4 = W4v[4 * (MT) + q];                 \
        _Pragma("unroll")                                                         \
        for (int r = 0; r < 4; ++r) {                                             \
            float h, g; tanh_sech2_t(fmaf(Ch[r], K2L, bb[r]), h, g);              \
            const float ax = Cx[r], ay = Cy[r], az = Cz[r];                       \
            const float qn = fmaf(ax, ax, fmaf(ay, ay, az * az));                 \
            tot = fmaf(g * fmaf(-(h + h), qn, Cs[r]), w4[r], tot);                \
        } }

#pragma unroll 1
    for (int t = 0; t < NBATCH; ++t) {
        const float x0 = nx0, x1 = nx1, x2 = nx2, sg = nsg;
        const long sn = sbase + ((t + 1) & 3) * 16 + sb;   // wraps on last iter (benign)
        nx0 = x_r[sn * 3]; nx1 = x_r[sn * 3 + 1]; nx2 = x_r[sn * 3 + 2];
        nsg = sigma_r[sn];

        // ---- layer 1 straight into B2 fragments (pure SSA assembly) ----
        L1K(0, Bh0, Bx0, By0, Bz0, Bs0)
        L1K(1, Bh1, Bx1, By1, Bz1, Bs1)

        // ---- layer 2: 4 mt tiles -> per-tile h4 quads -> B3 fragments ----
        L2MT(0, q0h, q0x, q0y, q0z, q0s)
        L2MT(1, q1h, q1x, q1y, q1z, q1s)
        const h8 Nh0 = cat4(q0h, q1h), Nx0 = cat4(q0x, q1x), Ny0 = cat4(q0y, q1y),
                 Nz0 = cat4(q0z, q1z), Ns0 = cat4(q0s, q1s);
        L2MT(2, q2h, q2x, q2y, q2z, q2s)
        L2MT(3, q3h, q3x, q3y, q3z, q3s)
        const h8 Nh1 = cat4(q2h, q3h), Nx1 = cat4(q2x, q3x), Ny1 = cat4(q2y, q3y),
                 Nz1 = cat4(q2z, q3z), Ns1 = cat4(q2s, q3s);

        // ---- layer 3 + W4 dot ----
        float tot = 0.f;
        L3MT(0) L3MT(1) L3MT(2) L3MT(3)

        tot += __shfl_xor(tot, 16);
        tot += __shfl_xor(tot, 32);
        if (lane < 16) out[sbase + t * 16 + sb] = sg * tot;
    }
}

extern "C" void kernel_launch(void* const* d_in, const int* in_sizes, int n_in,
                              void* d_out, int out_size, void* d_ws, size_t ws_size,
                              hipStream_t stream) {
    const float* x_r     = (const float*)d_in[0];
    const float* sigma_r = (const float*)d_in[1];
    const float* W1      = (const float*)d_in[2];
    const float* b1      = (const float*)d_in[3];
    const float* W2      = (const float*)d_in[4];
    const float* b2      = (const float*)d_in[5];
    const float* W3      = (const float*)d_in[6];
    const float* b3      = (const float*)d_in[7];
    const float* W4      = (const float*)d_in[8];
    float* out = (float*)d_out;

    pinn_mfma_kernel<<<NBLOCKS, 256, 0, stream>>>(
        x_r, sigma_r, W1, b1, W2, b2, W3, b3, W4, out);
}

// Round 9
// 137.937 us; speedup vs baseline: 1.1136x; 1.0942x over previous
//
#include <hip/hip_runtime.h>

typedef __fp16 f16;
typedef f16  h8 __attribute__((ext_vector_type(8)));
typedef float f4 __attribute__((ext_vector_type(4)));
typedef unsigned u32t;

#define NBLOCKS 1024
#define WPB 4
#define SPW 64
#define NBATCH 4
#define XSTR 36                  // u32 per sample row (bank spread, 16B-aligned)
#define XST  (16 * XSTR)         // 576 u32 per state buffer
#define K2L 2.8853900817779268f  // 2*log2(e): e^{2a} = 2^{K2L*a}

union H8u { h8 v; u32t u[4]; };
union U4h { uint4 u; h8 v; };

__device__ __forceinline__ u32t pk2(float a, float b) {
    return __builtin_bit_cast(u32t, __builtin_amdgcn_cvt_pkrtz(a, b));
}

// h = tanh(a), g = sech^2(a) given t = K2L*a (E = 2^t = e^{2a}); NaN-free at sat.
__device__ __forceinline__ void tanh_sech2_t(float t, float& h, float& g) {
    float E = __builtin_amdgcn_exp2f(t);
    float inv = __builtin_amdgcn_rcpf(E + 1.f);
    float u = inv + inv;
    h = 1.f - u;
    g = u * (2.f - u);
}

#define MF(A, B, C) C = __builtin_amdgcn_mfma_f32_16x16x32_f16(A, B, C, 0, 0, 0)

// R9: back to the R4 skeleton (register A-frags + LDS exchange; FETCH was 2.3MB,
// no scratch). R5-R8's A-in-LDS/pi3 structure carried 350-450MB of scratch
// traffic regardless of fragment-assembly style -- abandoned. New here vs R4:
// (1) 3-state exchange buffers with in-order-DS overwrite (z,s held in named
// uint2s until slots 0/1 are read) -> LDS 48KB -> 30KB -> 5 blocks/CU, so all
// 1024 blocks co-resident, no occupancy tail; (2) exp2-folded tanh.
__global__ __launch_bounds__(256, 3) void pinn_mfma_kernel(
    const float* __restrict__ x_r, const float* __restrict__ sigma_r,
    const float* __restrict__ W1, const float* __restrict__ b1,
    const float* __restrict__ W2, const float* __restrict__ b2,
    const float* __restrict__ W3, const float* __restrict__ b3,
    const float* __restrict__ W4, float* __restrict__ out)
{
    __shared__ f4 Wk[64];                // (K*w1x, K*w1y, K*w1z, K*b1)
    __shared__ f4 Wd[64];                // (w1x, w1y, w1z, -2*Q1)
    __shared__ f4 BbK2[16], BbK3[16], W4v[16];
    __shared__ u32t xch[WPB][3][XST];    // 27.6 KB, per-wave 3-slot exchange

    const int tid = threadIdx.x, lane = tid & 63, wv = tid >> 6;
    const int sb = lane & 15;   // sample slot (B/C col)
    const int q  = lane >> 4;   // lane quarter

    if (tid < 64) {
        float wx = W1[tid], wy = W1[64 + tid], wz = W1[128 + tid];
        f4 a; a[0] = K2L * wx; a[1] = K2L * wy; a[2] = K2L * wz; a[3] = K2L * b1[tid];
        Wk[tid] = a;
        f4 d; d[0] = wx; d[1] = wy; d[2] = wz; d[3] = -2.f * (wx*wx + wy*wy + wz*wz);
        Wd[tid] = d;
        ((float*)BbK2)[tid] = K2L * b2[tid];
        ((float*)BbK3)[tid] = K2L * b3[tid];
        ((float*)W4v)[tid]  = W4[tid];
    }
    __syncthreads();   // the only barrier

    // ---- A-fragments in registers (R4-verbatim): A[m][k] = W[32kk+8q+e][16mt+sb] ----
    h8 A2f[4][2], A3f[4][2];
#pragma unroll
    for (int mt = 0; mt < 4; ++mt)
#pragma unroll
    for (int kk = 0; kk < 2; ++kk) {
        H8u t2, t3;
#pragma unroll
        for (int p = 0; p < 4; ++p) {
            const int r0 = (32 * kk + 8 * q + 2 * p) * 64 + 16 * mt + sb;
            t2.u[p] = pk2(W2[r0], W2[r0 + 64]);
            t3.u[p] = pk2(W3[r0], W3[r0 + 64]);
        }
        A2f[mt][kk] = t2.v; A3f[mt][kk] = t3.v;
    }

    u32t (*xb)[XST] = xch[wv];
    const int wbase = sb * XSTR + 2 * q;   // b64 writes; +8 per mt
    const int rbase = sb * XSTR + 4 * q;   // b128 reads; +16 for kk=1

    const long sbase = ((long)blockIdx.x * WPB + wv) * SPW;
    float nx0 = x_r[(sbase + sb) * 3], nx1 = x_r[(sbase + sb) * 3 + 1],
          nx2 = x_r[(sbase + sb) * 3 + 2], nsg = sigma_r[sbase + sb];

#define RDB(Bf, st) { U4h u0, u1;                                                 \
    u0.u = *(const uint4*)&xb[(st)][rbase];                                       \
    u1.u = *(const uint4*)&xb[(st)][rbase + 16];                                  \
    Bf[0].v = u0.v; Bf[1].v = u1.v; }

// layer 2, one mt tile: 10 MFMA -> NL -> write h,x,y to slots 0/1/2; hold z,s
// in named uint2s (written to slots 0/1 after those are read -- in-order DS).
#define L2MT(MT, ZV, SV)                                                          \
    uint2 ZV, SV; {                                                               \
        f4 Ch = {0,0,0,0}, Cx = {0,0,0,0}, Cy = {0,0,0,0}, Cz = {0,0,0,0}, Cs = {0,0,0,0}; \
        _Pragma("unroll")                                                         \
        for (int kk = 0; kk < 2; ++kk) {                                          \
            const h8 A = A2f[(MT)][kk];                                           \
            MF(A, Bh[kk].v, Ch); MF(A, Bx[kk].v, Cx); MF(A, By[kk].v, Cy);        \
            MF(A, Bz[kk].v, Cz); MF(A, Bs[kk].v, Cs);                             \
        }                                                                         \
        const f4 bb = BbK2[4 * (MT) + q];                                         \
        float oh[4], ox[4], oy[4], oz[4], os[4];                                  \
        _Pragma("unroll")                                                         \
        for (int r = 0; r < 4; ++r) {                                             \
            float h, g; tanh_sech2_t(fmaf(Ch[r], K2L, bb[r]), h, g);              \
            const float ax = Cx[r], ay = Cy[r], az = Cz[r];                       \
            const float qn = fmaf(ax, ax, fmaf(ay, ay, az * az));                 \
            oh[r] = h; ox[r] = g * ax; oy[r] = g * ay; oz[r] = g * az;            \
            os[r] = g * fmaf(-(h + h), qn, Cs[r]);                                \
        }                                                                         \
        const int wo = wbase + 8 * (MT);                                          \
        *(uint2*)&xb[0][wo] = make_uint2(pk2(oh[0], oh[1]), pk2(oh[2], oh[3]));   \
        *(uint2*)&xb[1][wo] = make_uint2(pk2(ox[0], ox[1]), pk2(ox[2], ox[3]));   \
        *(uint2*)&xb[2][wo] = make_uint2(pk2(oy[0], oy[1]), pk2(oy[2], oy[3]));   \
        ZV = make_uint2(pk2(oz[0], oz[1]), pk2(oz[2], oz[3]));                    \
        SV = make_uint2(pk2(os[0], os[1]), pk2(os[2], os[3])); }

#pragma unroll 1
    for (int t = 0; t < NBATCH; ++t) {
        const float x0 = nx0, x1 = nx1, x2 = nx2, sg = nsg;
        const long sn = sbase + ((t + 1) & 3) * 16 + sb;   // wraps on last iter (benign)
        nx0 = x_r[sn * 3]; nx1 = x_r[sn * 3 + 1]; nx2 = x_r[sn * 3 + 2];
        nsg = sigma_r[sn];

        // ---- layer 1 straight into B2 fragments (R4-verbatim, exp2 tanh) ----
        H8u Bh[2], Bx[2], By[2], Bz[2], Bs[2];
#pragma unroll
        for (int kk = 0; kk < 2; ++kk)
#pragma unroll
        for (int p = 0; p < 4; ++p) {
            float hv[2], xv[2], yv[2], zv[2], sv[2];
#pragma unroll
            for (int o = 0; o < 2; ++o) {
                const int u = 32 * kk + 8 * q + 2 * p + o;
                const f4 wk = Wk[u], wd = Wd[u];
                const float tt = fmaf(wk[0], x0, fmaf(wk[1], x1, fmaf(wk[2], x2, wk[3])));
                float h, g; tanh_sech2_t(tt, h, g);
                hv[o] = h; xv[o] = g * wd[0]; yv[o] = g * wd[1]; zv[o] = g * wd[2];
                sv[o] = (h * g) * wd[3];
            }
            Bh[kk].u[p] = pk2(hv[0], hv[1]); Bx[kk].u[p] = pk2(xv[0], xv[1]);
            By[kk].u[p] = pk2(yv[0], yv[1]); Bz[kk].u[p] = pk2(zv[0], zv[1]);
            Bs[kk].u[p] = pk2(sv[0], sv[1]);
        }

        // ---- layer 2: 4 tiles; h,x,y -> LDS slots, z,s held in registers ----
        L2MT(0, z0, s0) L2MT(1, z1, s1) L2MT(2, z2, s2) L2MT(3, z3, s3)

        // ---- B3 fragments via 3-slot reuse (wave-private, in-order DS) ----
        H8u Nh[2], Nx[2], Ny[2], Nz[2], Ns[2];
        RDB(Nh, 0)
        *(uint2*)&xb[0][wbase]      = z0; *(uint2*)&xb[0][wbase + 8]  = z1;
        *(uint2*)&xb[0][wbase + 16] = z2; *(uint2*)&xb[0][wbase + 24] = z3;
        RDB(Nx, 1)
        *(uint2*)&xb[1][wbase]      = s0; *(uint2*)&xb[1][wbase + 8]  = s1;
        *(uint2*)&xb[1][wbase + 16] = s2; *(uint2*)&xb[1][wbase + 24] = s3;
        RDB(Ny, 2)
        RDB(Nz, 0)
        RDB(Ns, 1)

        // ---- layer 3 + W4 dot ----
        float tot = 0.f;
#pragma unroll
        for (int mt = 0; mt < 4; ++mt) {
            f4 Ch = {0,0,0,0}, Cx = {0,0,0,0}, Cy = {0,0,0,0}, Cz = {0,0,0,0}, Cs = {0,0,0,0};
#pragma unroll
            for (int kk = 0; kk < 2; ++kk) {
                const h8 A = A3f[mt][kk];
                MF(A, Nh[kk].v, Ch); MF(A, Nx[kk].v, Cx); MF(A, Ny[kk].v, Cy);
                MF(A, Nz[kk].v, Cz); MF(A, Ns[kk].v, Cs);
            }
            const f4 bb = BbK3[4 * mt + q], w4 = W4v[4 * mt + q];
#pragma unroll
            for (int r = 0; r < 4; ++r) {
                float h, g; tanh_sech2_t(fmaf(Ch[r], K2L, bb[r]), h, g);
                const float ax = Cx[r], ay = Cy[r], az = Cz[r];
                const float qn = fmaf(ax, ax, fmaf(ay, ay, az * az));
                const float sv = g * fmaf(-(h + h), qn, Cs[r]);
                tot = fmaf(sv, w4[r], tot);
            }
        }
        tot += __shfl_xor(tot, 16);
        tot += __shfl_xor(tot, 32);
        if (lane < 16) out[sbase + t * 16 + sb] = sg * tot;
    }
}

extern "C" void kernel_launch(void* const* d_in, const int* in_sizes, int n_in,
                              void* d_out, int out_size, void* d_ws, size_t ws_size,
                              hipStream_t stream) {
    const float* x_r     = (const float*)d_in[0];
    const float* sigma_r = (const float*)d_in[1];
    const float* W1      = (const float*)d_in[2];
    const float* b1      = (const float*)d_in[3];
    const float* W2      = (const float*)d_in[4];
    const float* b2      = (const float*)d_in[5];
    const float* W3      = (const float*)d_in[6];
    const float* b3      = (const float*)d_in[7];
    const float* W4      = (const float*)d_in[8];
    float* out = (float*)d_out;

    pinn_mfma_kernel<<<NBLOCKS, 256, 0, stream>>>(
        x_r, sigma_r, W1, b1, W2, b2, W3, b3, W4, out);
}

// Round 10
// 42.645 us; speedup vs baseline: 3.6020x; 3.2345x over previous
//
#include <hip/hip_runtime.h>

typedef __fp16 f16;
typedef f16  h8 __attribute__((ext_vector_type(8)));
typedef float f4 __attribute__((ext_vector_type(4)));
typedef unsigned u32t;

#define NBLOCKS 768              // = 256 CUs x 3 blocks/CU: ALL blocks co-resident
#define WPB 4
#define NWAVES (NBLOCKS * WPB)   // 3072
#define NBAT (262144 / 16)       // 16384 batches of 16 samples
#define XSTR 36                  // u32 per sample row (even, 16B-aligned rows)
#define XST  (16 * XSTR)         // u32 per state
#define K2L 2.8853900817779268f  // 2*log2(e):  e^{2a} = 2^{K2L*a}

union H8u { h8 v; u32t u[4]; };
union U4h { uint4 u; h8 v; };

__device__ __forceinline__ u32t pk2(float a, float b) {
    return __builtin_bit_cast(u32t, __builtin_amdgcn_cvt_pkrtz(a, b));
}

// h = tanh(a), g = sech^2(a) given t = K2L*a (E = 2^t = e^{2a}); NaN-free at sat.
// (validated in R9: absmax identical to __expf version)
__device__ __forceinline__ void tanh_sech2_t(float t, float& h, float& g) {
    float E = __builtin_amdgcn_exp2f(t);
    float inv = __builtin_amdgcn_rcpf(E + 1.f);
    float u = inv + inv;
    h = 1.f - u;
    g = u * (2.f - u);
}

// R10 = round-4 source (measured clean: FETCH 2.26MB, 44us) with exactly two
// zero-register-pressure deltas: (1) grid-stride over 768 fully-resident blocks
// (kills the 1-block/CU dispatch tail that held occupancy at 23%); (2) exp2-
// folded tanh with pre-scaled biases. R5-R9 all perturbed register liveness
// near the bounds=3 cap (~168 unified VGPR+AGPR) and spilled 270-450MB to
// scratch -- DO NOT add live state to this kernel.
__global__ __launch_bounds__(256, 3) void pinn_mfma_kernel(
    const float* __restrict__ x_r, const float* __restrict__ sigma_r,
    const float* __restrict__ W1, const float* __restrict__ b1,
    const float* __restrict__ W2, const float* __restrict__ b2,
    const float* __restrict__ W3, const float* __restrict__ b3,
    const float* __restrict__ W4, float* __restrict__ out)
{
    __shared__ f4 Wg[64];                   // (w1x, w1y, w1z, -2*Q1)
    __shared__ f4 Wb4[16], BbK2[16], BbK3[16], W4v[16];
    __shared__ u32t xch[WPB][5 * XST];      // f16-pair exchange, 46 KB

    const int tid = threadIdx.x, lane = tid & 63, wv = tid >> 6;
    const int sb = lane & 15;   // sample slot (B/C col)
    const int q  = lane >> 4;   // lane quarter (C row group / B k-chunk)

    if (tid < 64) {
        float wx = W1[tid], wy = W1[64 + tid], wz = W1[128 + tid];
        f4 w; w[0] = wx; w[1] = wy; w[2] = wz;
        w[3] = -2.f * (wx * wx + wy * wy + wz * wz);
        Wg[tid] = w;
        ((float*)Wb4)[tid]  = b1[tid];
        ((float*)BbK2)[tid] = K2L * b2[tid];
        ((float*)BbK3)[tid] = K2L * b3[tid];
        ((float*)W4v)[tid]  = W4[tid];
    }
    __syncthreads();   // the only barrier

    // ---- A-fragments (validated mapping): A[m][k] = W[32kk+8q+e][16mt+sb] ----
    h8 A2f[4][2], A3f[4][2];
#pragma unroll
    for (int mt = 0; mt < 4; ++mt)
#pragma unroll
    for (int kk = 0; kk < 2; ++kk) {
        H8u t2, t3;
#pragma unroll
        for (int p = 0; p < 4; ++p) {
            const int r0 = (32 * kk + 8 * q + 2 * p) * 64 + 16 * mt + sb;
            t2.u[p] = pk2(W2[r0], W2[r0 + 64]);
            t3.u[p] = pk2(W3[r0], W3[r0 + 64]);
        }
        A2f[mt][kk] = t2.v; A3f[mt][kk] = t3.v;
    }

    u32t* xb = xch[wv];
    const int wbase = sb * XSTR + 2 * q;   // + 8*mt + st*XST   (b64 writes)
    const int rbase = sb * XSTR + 4 * q;   // + 16*kk + st*XST  (b128 reads)

    const int wave_global = blockIdx.x * WPB + wv;

#define WR5(mt) { const int wo = wbase + 8 * (mt);                                         \
    *(uint2*)&xb[0 * XST + wo] = make_uint2(pk2(oh[0], oh[1]), pk2(oh[2], oh[3]));         \
    *(uint2*)&xb[1 * XST + wo] = make_uint2(pk2(ox[0], ox[1]), pk2(ox[2], ox[3]));         \
    *(uint2*)&xb[2 * XST + wo] = make_uint2(pk2(oy[0], oy[1]), pk2(oy[2], oy[3]));         \
    *(uint2*)&xb[3 * XST + wo] = make_uint2(pk2(oz[0], oz[1]), pk2(oz[2], oz[3]));         \
    *(uint2*)&xb[4 * XST + wo] = make_uint2(pk2(os[0], os[1]), pk2(os[2], os[3])); }

#define RDB(Bf, st) { U4h u0, u1;                                                          \
    u0.u = *(const uint4*)&xb[(st) * XST + rbase];                                         \
    u1.u = *(const uint4*)&xb[(st) * XST + rbase + 16];                                    \
    Bf[0] = u0.v; Bf[1] = u1.v; }

#define MFMA10(Af) _Pragma("unroll")                                                       \
    for (int kk = 0; kk < 2; ++kk) {                                                       \
        Ch = __builtin_amdgcn_mfma_f32_16x16x32_f16(Af[mt][kk], Bh[kk], Ch, 0, 0, 0);      \
        Cx = __builtin_amdgcn_mfma_f32_16x16x32_f16(Af[mt][kk], Bx[kk], Cx, 0, 0, 0);      \
        Cy = __builtin_amdgcn_mfma_f32_16x16x32_f16(Af[mt][kk], By[kk], Cy, 0, 0, 0);      \
        Cz = __builtin_amdgcn_mfma_f32_16x16x32_f16(Af[mt][kk], Bz[kk], Cz, 0, 0, 0);      \
        Cs = __builtin_amdgcn_mfma_f32_16x16x32_f16(Af[mt][kk], Bs[kk], Cs, 0, 0, 0);      \
    }

    // prefetch first batch
    int b = wave_global;
    {
        const long sp = (long)b * 16 + sb;
        // (declared below as loop-carried)
    }
    long sp0 = (long)b * 16 + sb;
    float nx0 = x_r[sp0 * 3], nx1 = x_r[sp0 * 3 + 1], nx2 = x_r[sp0 * 3 + 2],
          nsg = sigma_r[sp0];

#pragma unroll 1
    for (; b < NBAT; b += NWAVES) {
        const float x0 = nx0, x1 = nx1, x2 = nx2, sg = nsg;
        int bn = b + NWAVES;
        if (bn >= NBAT) bn = wave_global;      // dummy re-prefetch on last iter (benign)
        const long sn = (long)bn * 16 + sb;
        nx0 = x_r[sn * 3]; nx1 = x_r[sn * 3 + 1]; nx2 = x_r[sn * 3 + 2];
        nsg = sigma_r[sn];

        // ---- layer 1 in C layout (a = W1.x + b1; derivs from Wg), pack, write ----
#pragma unroll
        for (int mt = 0; mt < 4; ++mt) {
            const f4 bb = Wb4[4 * mt + q];
            float oh[4], ox[4], oy[4], oz[4], os[4];
#pragma unroll
            for (int r = 0; r < 4; ++r) {
                const f4 w = Wg[16 * mt + 4 * q + r];
                const float a = fmaf(w[0], x0, fmaf(w[1], x1, fmaf(w[2], x2, bb[r])));
                float h, g; tanh_sech2_t(K2L * a, h, g);
                oh[r] = h; ox[r] = g * w[0]; oy[r] = g * w[1]; oz[r] = g * w[2];
                os[r] = (h * g) * w[3];               // -2*h*g*Q1
            }
            WR5(mt)
        }

        // ---- B-fragments for layer 2 (in-order DS: reads after writes) ----
        h8 Bh[2], Bx[2], By[2], Bz[2], Bs[2];
        RDB(Bh, 0) RDB(Bx, 1) RDB(By, 2) RDB(Bz, 3) RDB(Bs, 4)

        // ---- layer 2: per-mt MFMA -> NL -> pack -> write ----
#pragma unroll
        for (int mt = 0; mt < 4; ++mt) {
            f4 Ch = {0.f,0.f,0.f,0.f}, Cx = {0.f,0.f,0.f,0.f}, Cy = {0.f,0.f,0.f,0.f},
               Cz = {0.f,0.f,0.f,0.f}, Cs = {0.f,0.f,0.f,0.f};
            MFMA10(A2f)
            const f4 bb = BbK2[4 * mt + q];
            float oh[4], ox[4], oy[4], oz[4], os[4];
#pragma unroll
            for (int r = 0; r < 4; ++r) {
                float h, g; tanh_sech2_t(fmaf(Ch[r], K2L, bb[r]), h, g);
                const float ax = Cx[r], ay = Cy[r], az = Cz[r];
                const float qq  = fmaf(ax, ax, fmaf(ay, ay, az * az));
                const float hg2 = (h * g) * 2.f;
                oh[r] = h; ox[r] = g * ax; oy[r] = g * ay; oz[r] = g * az;
                os[r] = fmaf(g, Cs[r], -(hg2 * qq));
            }
            WR5(mt)
        }

        // ---- B-fragments for layer 3 ----
        RDB(Bh, 0) RDB(Bx, 1) RDB(By, 2) RDB(Bz, 3) RDB(Bs, 4)

        // ---- layer 3: per-mt MFMA -> NL -> dot with W4 ----
        float tot = 0.f;
#pragma unroll
        for (int mt = 0; mt < 4; ++mt) {
            f4 Ch = {0.f,0.f,0.f,0.f}, Cx = {0.f,0.f,0.f,0.f}, Cy = {0.f,0.f,0.f,0.f},
               Cz = {0.f,0.f,0.f,0.f}, Cs = {0.f,0.f,0.f,0.f};
            MFMA10(A3f)
            const f4 bb = BbK3[4 * mt + q], w4 = W4v[4 * mt + q];
#pragma unroll
            for (int r = 0; r < 4; ++r) {
                float h, g; tanh_sech2_t(fmaf(Ch[r], K2L, bb[r]), h, g);
                const float ax = Cx[r], ay = Cy[r], az = Cz[r];
                const float qq  = fmaf(ax, ax, fmaf(ay, ay, az * az));
                const float hg2 = (h * g) * 2.f;
                const float sv  = fmaf(g, Cs[r], -(hg2 * qq));
                tot = fmaf(sv, w4[r], tot);
            }
        }
        tot += __shfl_xor(tot, 16);
        tot += __shfl_xor(tot, 32);
        if (lane < 16) out[(long)b * 16 + sb] = sg * tot;
    }
}

extern "C" void kernel_launch(void* const* d_in, const int* in_sizes, int n_in,
                              void* d_out, int out_size, void* d_ws, size_t ws_size,
                              hipStream_t stream) {
    const float* x_r     = (const float*)d_in[0];
    const float* sigma_r = (const float*)d_in[1];
    const float* W1      = (const float*)d_in[2];
    const float* b1      = (const float*)d_in[3];
    const float* W2      = (const float*)d_in[4];
    const float* b2      = (const float*)d_in[5];
    const float* W3      = (const float*)d_in[6];
    const float* b3      = (const float*)d_in[7];
    const float* W4      = (const float*)d_in[8];
    float* out = (float*)d_out;

    pinn_mfma_kernel<<<NBLOCKS, 256, 0, stream>>>(
        x_r, sigma_r, W1, b1, W2, b2, W3, b3, W4, out);
}